// Round 8
// baseline (221.113 us; speedup 1.0000x reference)
//
#include <hip/hip_runtime.h>
#include <cstdint>
#include <cstddef>

// ---------------------------------------------------------------------------
// MultiHeadAttention forward, MI355X/gfx950.
// cvt(fp32->bf16) -> fused QKV GEMM (MFMA) -> flash attention -> out-proj.
// MFMA layouts (m89/m91/m120):
//   K=32 A-frag: lane l holds A[m=l&15][k=(l>>4)*8+j], j=0..7
//   K=32 B-frag: lane l holds Bt[n=l&15][k=(l>>4)*8+j]
//   C/D: lane l, reg r holds D[m=(l>>4)*4+r][n=l&15]
// R14b: identical to R14 except the prologue SM() call signature (compile
// fix). Offset software pipeline in attn. R13 (53.9us) accounting: MFMA 35k,
// VALU 61k, LDS ~54k cycles of a 129k total -- no pipe saturated, and TLP is
// structurally capped at 2 waves/SIMD (2048 waves at 32q/wave; fewer q/wave
// doubles LDS traffic). Remaining lever: the serial QK->SM->PV chain leaves
// MFMA idle during SM and VALU idle during PV. Fix: PV lags one tile --
// iteration t does {stage(t+2); QK(t); PV(t-1); SM(t)} so PV(t-1) MFMAs
// grind while SM(t) VALU runs. Online-softmax stays exact: Oacc/Racc are at
// scale m(t-1)<=m(t) when PV(t-1) lands; SM(t)'s (rare, defer-max) rescale
// is ordered after PV(t-1) by the Oacc dependency.
// Buffering: PV(t-1) keeps buf(t-1) live through iter t => 4 buffers at
// KVBLK=64 (4 x (K 8KB + V 8KB) = 64KB LDS, unchanged occupancy). stage(t+2)
// gets ~2 iterations of DMA cover. Per-wave MFMA/exp2/LDS totals identical
// to R13; only the schedule changes.
// Kept: 4 waves x 32 q (2 groups of 16) sharing K/V LDS reads, XCD swizzle,
// XOR-swizzled unpadded K/V LDS, ones-MFMA Racc rowsum, K=32 PV, max3-tree
// rmax, defer-max THR=8, exp2 domain (QSCALE folded), separate cvt7 (R12
// fusion falsified), single-buffered projection GEMMs (R11 falsified).
// ---------------------------------------------------------------------------

#define D_MODEL 1024
#define NHEAD   16
#define HDIM    64
#define BATCH   2
#define SEQ     2048
#define BT      (BATCH * SEQ)   // 4096

// (1/sqrt(HDIM)) * log2(e) -- folds softmax scale + exp->exp2 conversion
#define QSCALE 0.18033688011112043f

typedef __bf16 bf16;
typedef __bf16 bf16x8 __attribute__((ext_vector_type(8)));
typedef __bf16 bf16x4 __attribute__((ext_vector_type(4)));
typedef float  floatx4 __attribute__((ext_vector_type(4)));
typedef short  short4v __attribute__((ext_vector_type(4)));

#define MFMA16(a, b, c) __builtin_amdgcn_mfma_f32_16x16x32_bf16((a), (b), (c), 0, 0, 0)

__device__ __forceinline__ float fexp2(float x) {
  return __builtin_amdgcn_exp2f(x);   // v_exp_f32: D = 2^S0
}

// async global->LDS, 16B per lane. LDS dest = wave-uniform base + lane*16.
__device__ __forceinline__ void async_cp16(const bf16* g, bf16* l) {
  __builtin_amdgcn_global_load_lds(
      (__attribute__((address_space(1))) void*)(g),
      (__attribute__((address_space(3))) void*)(l), 16, 0, 0);
}

// ---------------------------------------------------------------------------
// fp32 -> bf16 conversion for q,k,v and the 4 weight matrices.
// ---------------------------------------------------------------------------
__global__ __launch_bounds__(256) void cvt7(
    const float* __restrict__ s0, const float* __restrict__ s1,
    const float* __restrict__ s2, const float* __restrict__ s3,
    const float* __restrict__ s4, const float* __restrict__ s5,
    const float* __restrict__ s6,
    bf16* __restrict__ d0, bf16* __restrict__ d1, bf16* __restrict__ d2,
    bf16* __restrict__ d3, bf16* __restrict__ d4, bf16* __restrict__ d5,
    bf16* __restrict__ d6)
{
  const float* src; bf16* dst; int n4;
  switch (blockIdx.y) {
    case 0:  src = s0; dst = d0; n4 = (BT * D_MODEL) / 4; break;
    case 1:  src = s1; dst = d1; n4 = (BT * D_MODEL) / 4; break;
    case 2:  src = s2; dst = d2; n4 = (BT * D_MODEL) / 4; break;
    case 3:  src = s3; dst = d3; n4 = (D_MODEL * D_MODEL) / 4; break;
    case 4:  src = s4; dst = d4; n4 = (D_MODEL * D_MODEL) / 4; break;
    case 5:  src = s5; dst = d5; n4 = (D_MODEL * D_MODEL) / 4; break;
    default: src = s6; dst = d6; n4 = (D_MODEL * D_MODEL) / 4; break;
  }
  int stride = gridDim.x * blockDim.x;
  for (int i = blockIdx.x * blockDim.x + threadIdx.x; i < n4; i += stride) {
    float4 f = ((const float4*)src)[i];
    bf16x4 h;
    h[0] = (bf16)f.x; h[1] = (bf16)f.y; h[2] = (bf16)f.z; h[3] = (bf16)f.w;
    ((bf16x4*)dst)[i] = h;
  }
}

// ---------------------------------------------------------------------------
// 128x128-tile GEMM core, K=1024, BK=32 (m97 structure, single-buffered:
// TLP across 3 blocks/CU hides staging latency; explicit dbuf regressed R11).
// ---------------------------------------------------------------------------
__device__ __forceinline__ void gemm128_core(
    const bf16* __restrict__ A, const bf16* __restrict__ W,
    int m0, int n0, bf16* As, bf16* Bs, floatx4 acc[4][4])
{
  const int t = threadIdx.x;
  const int l = t & 63, w = t >> 6;
  const int quad = l >> 4, lr = l & 15;
  const int wm = (w >> 1) * 64, wn = (w & 1) * 64;

  floatx4 z = {0.f, 0.f, 0.f, 0.f};
#pragma unroll
  for (int i = 0; i < 4; i++)
#pragma unroll
    for (int j = 0; j < 4; j++) acc[i][j] = z;

  for (int kt = 0; kt < 1024; kt += 32) {
    __syncthreads();
#pragma unroll
    for (int i = 0; i < 2; i++) {
      int c = i * 256 + t;
      int row = c >> 2, ci = c & 3;
      async_cp16(A + (size_t)(m0 + row) * 1024 + kt + ci * 8,
                 As + (i * 256 + w * 64) * 8);
      async_cp16(W + (size_t)(n0 + row) * 1024 + kt + ci * 8,
                 Bs + (i * 256 + w * 64) * 8);
    }
    __syncthreads();

    bf16x8 af[4], bfr[4];
#pragma unroll
    for (int i = 0; i < 4; i++) {
      af[i]  = *(const bf16x8*)(As + (wm + i * 16 + lr) * 32 + quad * 8);
      bfr[i] = *(const bf16x8*)(Bs + (wn + i * 16 + lr) * 32 + quad * 8);
    }
#pragma unroll
    for (int i = 0; i < 4; i++)
#pragma unroll
      for (int j = 0; j < 4; j++)
        acc[i][j] = MFMA16(af[i], bfr[j], acc[i][j]);
  }
}

// ---------------------------------------------------------------------------
// Fused QKV projection. zid selects (q,Wq)->qh, (k,Wk)->kh, (v,Wv)->vt.
// qh,kh: [B*H][T][64]; v stored TRANSPOSED [B*H][64][T].
// qh is pre-scaled by QSCALE (softmax scale folded + exp2 domain).
// ---------------------------------------------------------------------------
__global__ __launch_bounds__(256) void qkv_gemm(
    const bf16* __restrict__ qb, const bf16* __restrict__ kb, const bf16* __restrict__ vb,
    const bf16* __restrict__ wq, const bf16* __restrict__ wk, const bf16* __restrict__ wv,
    const float* __restrict__ biasq, const float* __restrict__ biask, const float* __restrict__ biasv,
    bf16* __restrict__ qh, bf16* __restrict__ kh, bf16* __restrict__ vt)
{
  __shared__ bf16 As[128 * 32];
  __shared__ bf16 Bs[128 * 32];
  const int zid = blockIdx.z;
  const bf16* A = (zid == 0) ? qb : ((zid == 1) ? kb : vb);
  const bf16* W = (zid == 0) ? wq : ((zid == 1) ? wk : wv);
  const float* bias = (zid == 0) ? biasq : ((zid == 1) ? biask : biasv);
  const int m0 = blockIdx.x * 128, n0 = blockIdx.y * 128;

  floatx4 acc[4][4];
  gemm128_core(A, W, m0, n0, As, Bs, acc);

  const int t = threadIdx.x, l = t & 63, w = t >> 6;
  const int quad = l >> 4, lr = l & 15;
  const int wm = (w >> 1) * 64, wn = (w & 1) * 64;
  const float sc = (zid == 0) ? QSCALE : 1.0f;

  if (zid < 2) {
    bf16* out = (zid == 0) ? qh : kh;
#pragma unroll
    for (int i = 0; i < 4; i++) {
      int mbase = m0 + wm + i * 16 + quad * 4;       // global row (b*2048+t)
      int b  = mbase >> 11;
      int tq = mbase & 2047;
#pragma unroll
      for (int j = 0; j < 4; j++) {
        int n = n0 + wn + j * 16 + lr;               // e = h*64 + dh
        float bv = bias[n];
        int h = n >> 6, dh = n & 63;
        bf16* p = out + ((size_t)((b * NHEAD + h) * SEQ + tq)) * HDIM + dh;
#pragma unroll
        for (int r = 0; r < 4; r++)
          p[(size_t)r * HDIM] = (bf16)((acc[i][j][r] + bv) * sc);
      }
    }
  } else {
#pragma unroll
    for (int i = 0; i < 4; i++) {
      int mbase = m0 + wm + i * 16 + quad * 4;
      int b  = mbase >> 11;
      int tq = mbase & 2047;
#pragma unroll
      for (int j = 0; j < 4; j++) {
        int n = n0 + wn + j * 16 + lr;
        float bv = bias[n];
        int h = n >> 6, dh = n & 63;
        bf16x4 pk;
#pragma unroll
        for (int r = 0; r < 4; r++) pk[r] = (bf16)(acc[i][j][r] + bv);
        *(bf16x4*)(vt + ((size_t)((b * NHEAD + h) * HDIM + dh)) * SEQ + tq) = pk;
      }
    }
  }
}

// ---------------------------------------------------------------------------
// Flash attention, offset-pipelined. Grid (T/128, B*H), block 256 = 4 waves;
// wave w owns q-rows qt0 + w*32 + {0..31} as TWO groups of 16 (g=0,1;
// q = g*16 + lr); KVBLK=64 keys/tile, 32 tiles.
// LDS: 4 buffers x (K 8KB + V 8KB) = 64KB.
//   K  [64 keys][64 el], 8-el chunk ci at phys ci ^ (krow & 7)
//   V^T[64 d   ][64 el], 8-el chunk ci at phys ci ^ (vrow & 7)
// Iteration t: barrier; stage(t+2 -> (t+2)&3); QK(t) from buf t&3;
// PV(t-1) from buf (t-1)&3 (MFMA pipe, overlaps SM(t) VALU); SM(t) -> pk.
// Buffer states at iter t: t&3 QK-live, (t-1)&3 PV-live, (t+1)&3 DMA
// in-flight, (t+2)&3 == (t-2)&3 free (PV(t-2) done last iter). DMA issued
// at iter t drains at barrier(t+2): ~2 iterations of cover.
// Epilogue: PV(31); normalize by Racc[0]; LDS transpose; coalesced store.
// ---------------------------------------------------------------------------
__global__ __launch_bounds__(256, 2) void attn_fused(
    const bf16* __restrict__ qh, const bf16* __restrict__ kh,
    const bf16* __restrict__ vt, bf16* __restrict__ attn)
{
  __shared__ __align__(16) char smem[65536];   // 4 x (K 8KB + V 8KB)

  const int t = threadIdx.x, l = t & 63, w = t >> 6;   // w in 0..3
  const int quad = l >> 4, lr = l & 15;

  // XCD swizzle: linear block id % 8 = XCD. XCD x gets heads {x, x+8, x+16,
  // x+24}, all 16 q-tiles each: bijective over the 512-block grid.
  const int hb  = blockIdx.y * 16 + blockIdx.x;   // dispatch-linear id
  const int j   = hb >> 3;
  const int bh  = (hb & 7) + ((j & 3) << 3);
  const int qt0 = (j >> 2) * 128;

  const bf16* qg = qh + (size_t)bh * SEQ * HDIM;
  const bf16* kg = kh + (size_t)bh * SEQ * HDIM;
  const bf16* vg = vt + (size_t)bh * HDIM * SEQ;

  // Staging geometry (per wave, per tile): 2 K-segments + 2 V-segments,
  // segment index s = w*2 + i (8 segs of 1KB each for K and for V).
  // K seg s: key-rows s*8+(l>>3), phys chunk l&7 <- global chunk (l&7)^(row&7)
  // V seg s: d-rows   s*8+(l>>3), phys chunk l&7 <- global chunk (l&7)^(row&7)
  const bf16* kseg[2];
  const bf16* vseg[2];
#pragma unroll
  for (int i = 0; i < 2; i++) {
    int s = w * 2 + i;
    int row = s * 8 + (l >> 3);
    kseg[i] = kg + (size_t)row * HDIM + (((l & 7) ^ (row & 7)) * 8);
    vseg[i] = vg + (size_t)row * SEQ + (((l & 7) ^ (row & 7)) * 8);
  }

  // Q B-frags (K=32) for the wave's 32 q-rows: q = qt0 + w*32 + g*16 + lr.
  bf16x8 qf[2][2];
#pragma unroll
  for (int g = 0; g < 2; g++)
#pragma unroll
    for (int ko = 0; ko < 2; ko++)
      qf[g][ko] = *(const bf16x8*)(qg + (size_t)(qt0 + w * 32 + g * 16 + lr) * HDIM
                                   + ko * 32 + quad * 8);

  const floatx4 zz = {0.f, 0.f, 0.f, 0.f};
  floatx4 Oacc[2][4];   // [g] O^T[d = dt*16 + quad*4 + r][q = lr]
#pragma unroll
  for (int g = 0; g < 2; g++)
#pragma unroll
    for (int dt = 0; dt < 4; dt++) Oacc[g][dt] = zz;
  floatx4 Racc[2] = {zz, zz};   // rowsum(P) accum; all regs equal the sum
  float mrow[2] = {-3.0e38f, -3.0e38f};

  bf16x8 ones8;
#pragma unroll
  for (int i = 0; i < 8; i++) ones8[i] = (bf16)1.0f;

  auto stage = [&](int buf, int kt) {
    bf16* Kb = (bf16*)(smem + buf * 16384);
    bf16* Vb = (bf16*)(smem + buf * 16384 + 8192);
    int off = kt * 64;
#pragma unroll
    for (int i = 0; i < 2; i++) {
      async_cp16(kseg[i] + (size_t)off * HDIM, Kb + (w * 2 + i) * 512);
      async_cp16(vseg[i] + off,                Vb + (w * 2 + i) * 512);
    }
  };

  // QK for tile in buffer buf -> s0/s1 (lane: S[q=lr][key=ni*16+quad*4+r]).
  floatx4 s0[4], s1[4];
  auto QK = [&](int buf) {
    const bf16* Ks = (const bf16*)(smem + buf * 16384);
    const bf16* krow0 = Ks + lr * 64 + ((quad ^ (lr & 7)) * 8);
    const bf16* krow1 = Ks + lr * 64 + (((quad + 4) ^ (lr & 7)) * 8);
#pragma unroll
    for (int ni = 0; ni < 4; ni++) {
      bf16x8 k0 = *(const bf16x8*)(krow0 + ni * 1024);
      bf16x8 k1 = *(const bf16x8*)(krow1 + ni * 1024);
      floatx4 a0 = MFMA16(k0, qf[0][0], zz);
      floatx4 a1 = MFMA16(k0, qf[1][0], zz);
      a0 = MFMA16(k1, qf[0][1], a0);
      a1 = MFMA16(k1, qf[1][1], a1);
      s0[ni] = a0;
      s1[ni] = a1;
    }
  };

  // Softmax on s0/s1 -> pk (K=32 B-frags: pkg[nip][0..3] = keys 2nip*16+
  // quad*4+r, [4..7] = (2nip+1)*16+quad*4+r), updates mrow/Oacc/Racc.
  bf16x8 pk0[2], pk1[2];
  auto SM = [&]() {
#pragma unroll
    for (int g = 0; g < 2; g++) {
      floatx4* sg = g ? s1 : s0;
      bf16x8* pkg = g ? pk1 : pk0;

      float xm[4];
#pragma unroll
      for (int ni = 0; ni < 4; ni++) {
        float m01 = fmaxf(sg[ni][0], sg[ni][1]);
        xm[ni] = fmaxf(fmaxf(m01, sg[ni][2]), sg[ni][3]);   // max3-fusable
      }
      float rmax = fmaxf(fmaxf(xm[0], xm[1]), fmaxf(xm[2], xm[3]));
      rmax = fmaxf(rmax, __shfl_xor(rmax, 16, 64));
      rmax = fmaxf(rmax, __shfl_xor(rmax, 32, 64));

      // defer-max (THR=8, exp2 domain): skip O/R rescale when no lane's max
      // grew by more than 8; P then bounded by 2^8, fp32 accum absorbs it.
      if (!__all(rmax - mrow[g] <= 8.0f)) {
        float mnew = fmaxf(mrow[g], rmax);
        float al = fexp2(mrow[g] - mnew);
        mrow[g] = mnew;
#pragma unroll
        for (int dt = 0; dt < 4; dt++)
#pragma unroll
          for (int r = 0; r < 4; r++) Oacc[g][dt][r] *= al;
#pragma unroll
        for (int r = 0; r < 4; r++) Racc[g][r] *= al;
      }

      const float m = mrow[g];
#pragma unroll
      for (int nip = 0; nip < 2; nip++) {
        bf16x8 pv;
#pragma unroll
        for (int r = 0; r < 4; r++) pv[r]     = (bf16)fexp2(sg[2*nip  ][r] - m);
#pragma unroll
        for (int r = 0; r < 4; r++) pv[4 + r] = (bf16)fexp2(sg[2*nip+1][r] - m);
        pkg[nip] = pv;
      }
    }
  };

  // PV (K=32) for the tile whose P is in pk, V in buffer buf.
  // k-slot (quad,j) -> key (2nip+(j>=4))*16 + quad*4 + (j&3); A-frag =
  // concat of V chunks 4nip+(quad>>1) and 4nip+2+(quad>>1) (phys = c ^
  // (lr&7), row = dt*16+lr, sub-offset (quad&1)*4). Racc += ones x P.
  auto PV = [&](int buf) {
    const bf16* Vts = (const bf16*)(smem + buf * 16384 + 8192);
    const bf16* vbase = Vts + lr * 64 + (quad & 1) * 4;
#pragma unroll
    for (int nip = 0; nip < 2; nip++) {
      const bf16* vpA = vbase + ((((4 * nip)     + (quad >> 1)) ^ (lr & 7)) * 8);
      const bf16* vpB = vbase + ((((4 * nip + 2) + (quad >> 1)) ^ (lr & 7)) * 8);
      Racc[0] = MFMA16(ones8, pk0[nip], Racc[0]);
      Racc[1] = MFMA16(ones8, pk1[nip], Racc[1]);
#pragma unroll
      for (int dt = 0; dt < 4; dt++) {
        bf16x4 va = *(const bf16x4*)(vpA + dt * 1024);
        bf16x4 vb = *(const bf16x4*)(vpB + dt * 1024);
        bf16x8 vf8 = __builtin_shufflevector(va, vb, 0, 1, 2, 3, 4, 5, 6, 7);
        Oacc[0][dt] = MFMA16(vf8, pk0[nip], Oacc[0][dt]);
        Oacc[1][dt] = MFMA16(vf8, pk1[nip], Oacc[1][dt]);
      }
    }
  };

  // ---- Offset pipeline ----
  stage(0, 0);
  stage(1, 1);
  __syncthreads();          // tiles 0,1 resident (vmcnt drain)
  stage(2, 2);
  QK(0);
  SM();
  for (int kt = 1; kt < 32; kt++) {
    __syncthreads();        // tile kt resident; buf (kt+2)&3 free
    if (kt + 2 < 32) stage((kt + 2) & 3, kt + 2);
    QK(kt & 3);
    PV((kt - 1) & 3);       // MFMA pipe: previous tile's PV ...
    SM();                   // ... overlaps this tile's softmax VALU
  }
  PV(31 & 3);

  // ---- Epilogue: normalize, transpose via LDS, coalesced store. ----
  // Ost overlays bufs 0/1 (tiles 28/29: consumed by PV(28)/PV(29) in iters
  // 29/30; all waves are past barrier(31), so the region is dead).
  bf16* Ost = (bf16*)smem;
#pragma unroll
  for (int g = 0; g < 2; g++) {
    float inv = 1.0f / Racc[g][0];
#pragma unroll
    for (int dt = 0; dt < 4; dt++) {
      bf16x4 ov;
#pragma unroll
      for (int r = 0; r < 4; r++) ov[r] = (bf16)(Oacc[g][dt][r] * inv);
      *(bf16x4*)(Ost + (size_t)(w * 32 + g * 16 + lr) * 72 + dt * 16 + quad * 4) = ov;
    }
  }
  __syncthreads();

  // stream Ost [128 q][64 d] to attn[b][qt0+row][h*64 + d], coalesced 16B.
  const int b = bh >> 4, h = bh & 15;
#pragma unroll
  for (int i = 0; i < 4; i++) {
    int c = t + 256 * i;
    int row = c >> 3, ci = c & 7;
    *(int4*)(attn + ((size_t)b * SEQ + qt0 + row) * D_MODEL + h * HDIM + ci * 8) =
        *(const int4*)(Ost + row * 72 + ci * 8);
  }
}

// ---------------------------------------------------------------------------
// Output projection: out = attn @ Wo^T + bo, fp32 output.
// 128x64 tiles, single-buffered (R10 structure). Grid (32,16) = 512 blocks.
// ---------------------------------------------------------------------------
__global__ __launch_bounds__(256) void oproj_gemm(
    const bf16* __restrict__ attn, const bf16* __restrict__ wo,
    const float* __restrict__ bo, float* __restrict__ out)
{
  __shared__ bf16 As[128 * 32];   // 8KB
  __shared__ bf16 Bs[64 * 32];    // 4KB
  const int m0 = blockIdx.x * 128, n0 = blockIdx.y * 64;
  const int t = threadIdx.x, l = t & 63, w = t >> 6;
  const int quad = l >> 4, lr = l & 15;
  const int wm = (w >> 1) * 64, wn = (w & 1) * 32;

  floatx4 z = {0.f, 0.f, 0.f, 0.f};
  floatx4 acc[4][2];
#pragma unroll
  for (int i = 0; i < 4; i++)
#pragma unroll
    for (int j = 0; j < 2; j++) acc[i][j] = z;

  for (int kt = 0; kt < 1024; kt += 32) {
    __syncthreads();
#pragma unroll
    for (int i = 0; i < 2; i++) {
      int c = i * 256 + t;
      int row = c >> 2, ci = c & 3;          // A: 128 rows x 4 chunks
      async_cp16(attn + (size_t)(m0 + row) * 1024 + kt + ci * 8,
                 As + (i * 256 + w * 64) * 8);
    }
    {
      int row = t >> 2, ci = t & 3;          // B: 64 rows x 4 chunks
      async_cp16(wo + (size_t)(n0 + row) * 1024 + kt + ci * 8,
                 Bs + (w * 64) * 8);
    }
    __syncthreads();

    bf16x8 af[4], bfr[2];
#pragma unroll
    for (int i = 0; i < 4; i++)
      af[i]  = *(const bf16x8*)(As + (wm + i * 16 + lr) * 32 + quad * 8);
#pragma unroll
    for (int j = 0; j < 2; j++)
      bfr[j] = *(const bf16x8*)(Bs + (wn + j * 16 + lr) * 32 + quad * 8);
#pragma unroll
    for (int i = 0; i < 4; i++)
#pragma unroll
      for (int j = 0; j < 2; j++)
        acc[i][j] = MFMA16(af[i], bfr[j], acc[i][j]);
  }

#pragma unroll
  for (int i = 0; i < 4; i++) {
    int m = m0 + wm + i * 16 + quad * 4;
#pragma unroll
    for (int j = 0; j < 2; j++) {
      int n = n0 + wn + j * 16 + lr;
      float bv = bo[n];
      float* p = out + (size_t)m * D_MODEL + n;
#pragma unroll
      for (int r = 0; r < 4; r++)
        p[(size_t)r * D_MODEL] = acc[i][j][r] + bv;
    }
  }
}

// ---------------------------------------------------------------------------
extern "C" void kernel_launch(void* const* d_in, const int* in_sizes, int n_in,
                              void* d_out, int out_size, void* d_ws, size_t ws_size,
                              hipStream_t stream)
{
  const float* q  = (const float*)d_in[0];
  const float* k  = (const float*)d_in[1];
  const float* v  = (const float*)d_in[2];
  const float* Wq = (const float*)d_in[3];
  const float* bq = (const float*)d_in[4];
  const float* Wk = (const float*)d_in[5];
  const float* bk = (const float*)d_in[6];
  const float* Wv = (const float*)d_in[7];
  const float* bv = (const float*)d_in[8];
  const float* Wo = (const float*)d_in[9];
  const float* bo = (const float*)d_in[10];

  const size_t NQ = (size_t)BT * D_MODEL;        // 4194304
  const size_t NW = (size_t)D_MODEL * D_MODEL;   // 1048576

  bf16* p = (bf16*)d_ws;
  bf16* qb   = p; p += NQ;
  bf16* kb   = p; p += NQ;
  bf16* vb   = p; p += NQ;
  bf16* wqb  = p; p += NW;
  bf16* wkb  = p; p += NW;
  bf16* wvb  = p; p += NW;
  bf16* wob  = p; p += NW;
  bf16* qhp  = p; p += NQ;   // [B*H][T][64], pre-scaled by QSCALE
  bf16* khp  = p; p += NQ;   // [B*H][T][64]
  bf16* vtp  = p; p += NQ;   // [B*H][64][T]
  bf16* attn = p; p += NQ;   // [B][T][1024]

  cvt7<<<dim3(1024, 7, 1), 256, 0, stream>>>(q, k, v, Wq, Wk, Wv, Wo,
                                             qb, kb, vb, wqb, wkb, wvb, wob);
  qkv_gemm<<<dim3(32, 8, 3), 256, 0, stream>>>(qb, kb, vb, wqb, wkb, wvb,
                                               bq, bk, bv, qhp, khp, vtp);
  attn_fused<<<dim3(16, 32, 1), 256, 0, stream>>>(qhp, khp, vtp, attn);
  oproj_gemm<<<dim3(32, 16, 1), 256, 0, stream>>>(attn, wob, bo, (float*)d_out);
}